// Round 11
// baseline (392.758 us; speedup 1.0000x reference)
//
#include <hip/hip_runtime.h>
#include <hip/hip_bf16.h>

// Problem constants (B=4, C=256, H=W=64, N=4096, G=32, DQK=32)
#define NB 4
#define CD 256
#define NT 4096
#define DQ 32

typedef __attribute__((ext_vector_type(8))) __bf16 bf16x8;
typedef __attribute__((ext_vector_type(16))) float float16v;
typedef __attribute__((ext_vector_type(4))) unsigned int uint4v;
typedef __attribute__((ext_vector_type(2))) unsigned int uint2v;

#if __has_builtin(__builtin_amdgcn_exp2f)
#define EXP2(x) __builtin_amdgcn_exp2f(x)
#else
#define EXP2(x) exp2f(x)
#endif

__device__ inline unsigned short f2bf(float f) {
  unsigned u = __float_as_uint(f);
  u += 0x7fffu + ((u >> 16) & 1u);
  return (unsigned short)(u >> 16);
}

// Raw barrier: LDS ordering only. Global loads into registers stay IN FLIGHT
// across it (compiler __syncthreads() forces vmcnt(0) drain = R7's 99us).
#define BARRIER() asm volatile("s_waitcnt lgkmcnt(0)\n\ts_barrier" ::: "memory")

// ---------------------------------------------------------------------------
// Stats + weight packing (unchanged).
// ---------------------------------------------------------------------------
__global__ __launch_bounds__(1024) void stats_pack(
    const float* __restrict__ x, const float* __restrict__ gamma,
    const float* __restrict__ beta, const float* __restrict__ wq,
    const float* __restrict__ wk, const float* __restrict__ wv,
    const float* __restrict__ wp, const float* __restrict__ bq,
    const float* __restrict__ bk, const float* __restrict__ bv,
    float* __restrict__ sc, float* __restrict__ sh,
    unsigned short* __restrict__ wqkv, unsigned short* __restrict__ wpb,
    float* __restrict__ bias) {
  int bx = blockIdx.x;
  int tid = threadIdx.x;
  if (bx < 128) {
    int b = bx >> 5, g = bx & 31;
    const float4* xp = (const float4*)(x + (size_t)bx * 32768);
    float s = 0.f, ss = 0.f;
#pragma unroll
    for (int i = 0; i < 8; i++) {
      float4 t4 = xp[i * 1024 + tid];
      s += t4.x + t4.y + t4.z + t4.w;
      ss += t4.x * t4.x + t4.y * t4.y + t4.z * t4.z + t4.w * t4.w;
    }
#pragma unroll
    for (int off = 32; off >= 1; off >>= 1) {
      s += __shfl_xor(s, off);
      ss += __shfl_xor(ss, off);
    }
    __shared__ float red[32];
    int wid = tid >> 6;
    if ((tid & 63) == 0) {
      red[wid] = s;
      red[16 + wid] = ss;
    }
    __syncthreads();
    if (tid < 8) {
      float S = 0.f, SS = 0.f;
#pragma unroll
      for (int i = 0; i < 16; i++) {
        S += red[i];
        SS += red[16 + i];
      }
      float mu = S * (1.f / 32768.f);
      float rstd = rsqrtf(SS * (1.f / 32768.f) - mu * mu + 1e-5f);
      int c = g * 8 + tid;
      float gm = gamma[c];
      sc[b * CD + c] = gm * rstd;
      sh[b * CD + c] = beta[c] - mu * gm * rstd;
    }
  } else {
    const float scale2 = 0.2550348909867343f;  // log2(e)/sqrt(32)
    int i = (bx - 128) * 1024 + tid;
    if (i < 320 * 256) {
      int j = i >> 8, c = i & 255;
      float v;
      if (j < 32) v = wq[j * 256 + c] * scale2;
      else if (j < 64) v = wk[(j - 32) * 256 + c];
      else v = wv[(j - 64) * 256 + c];
      wqkv[i] = f2bf(v);
    } else if (i < 320 * 256 + 256 * 256) {
      int k = i - 320 * 256;
      wpb[k] = f2bf(wp[k]);
    } else if (i < 320 * 256 + 256 * 256 + 320) {
      int j = i - (320 * 256 + 256 * 256);
      float v;
      if (j < 32) v = bq[j] * scale2;
      else if (j < 64) v = bk[j - 32];
      else v = bv[j - 64];
      bias[j] = v;
    }
  }
}

// ---------------------------------------------------------------------------
// Fused normalize + QKV GEMM (unchanged from R13).
// ---------------------------------------------------------------------------
__global__ __launch_bounds__(512) void qkv_norm(
    const float* __restrict__ x, const float* __restrict__ sc,
    const float* __restrict__ sh, const unsigned short* __restrict__ A,
    const float* __restrict__ bias, unsigned short* __restrict__ qk,
    unsigned short* __restrict__ v) {
  int nt = blockIdx.x, b = blockIdx.y;
  int tid = threadIdx.x, lane = tid & 63, w = tid >> 6;
  int l31 = lane & 31, hh = lane >> 5;
  int n0 = nt * 32;

  __shared__ unsigned short Hs[32 * 262];
  const float* xb = x + (size_t)b * CD * NT + n0;
  const float* scb = sc + b * CD;
  const float* shb = sh + b * CD;
  {
    int n_l = tid & 31, cg = tid >> 5;  // 16 c-groups of 16 channels
    int c0 = cg * 16;
    unsigned short hv[16];
#pragma unroll
    for (int j = 0; j < 16; j++) {
      float val = xb[(size_t)(c0 + j) * NT + n_l];
      hv[j] = f2bf(val * scb[c0 + j] + shb[c0 + j]);
    }
    *(uint4v*)&Hs[n_l * 262 + c0] = *(uint4v*)hv;
    *(uint4v*)&Hs[n_l * 262 + c0 + 8] = *(uint4v*)(hv + 8);
  }
  __syncthreads();

  int n = n0 + l31;
  int itg = n >> 6, sp = (n >> 4) & 3;
  int lsn = ((n >> 3) & 1) * 32;
  int el = n & 7;
  const unsigned short* Brow = &Hs[l31 * 262 + 8 * hh];
  for (int t = w; t < 10; t += 8) {
    int m_base = t * 32;
    const unsigned short* Arow = A + (size_t)(m_base + l31) * 256 + 8 * hh;
    float16v acc;
#pragma unroll
    for (int r = 0; r < 16; r++) acc[r] = 0.f;
#pragma unroll
    for (int s = 0; s < 16; s++) {
      bf16x8 af = *(const bf16x8*)(Arow + 16 * s);
      bf16x8 bf = *(const bf16x8*)(Brow + 16 * s);
      acc = __builtin_amdgcn_mfma_f32_32x32x16_bf16(af, bf, acc, 0, 0, 0);
    }
#pragma unroll
    for (int r = 0; r < 16; r++) {
      int j = m_base + (r & 3) + 8 * (r >> 2) + 4 * hh;
      float val = acc[r] + bias[j];
      if (j < 64) {
        qk[((size_t)b * NT + n) * 64 + j] = f2bf(val);
      } else {
        int e = j - 64;
        int et = e >> 5;
        v[((((size_t)b * 64 + itg) * 8 + et) * 4 + sp) * 512 +
          (lsn + (e & 31)) * 8 + el] = f2bf(val);
      }
    }
  }
}

// ---------------------------------------------------------------------------
// Fused attention R16: 32-row q-tiles -> 8 waves/SIMD without spilling.
// R14 autopsy: VGPR_Count=64 of the R11 kernel proves qfr/kreg alias across
// the wave-role branch; live state = vS(32)+acc(32)+shared(8)+addr ~ 64.
// Halving acc (one q-half per block) fits the 64-reg/8-wave budget:
// grid 1024 (4 blocks/CU, 128 per (b,kh) = one XCD, pin preserved),
// Pbuf halves -> LDS 35.8KB (4 blocks = 143KB < 160). QK: wave w<4 =
// (tp=w>>1 tile-of-pair, ks2=w&1 key-half), ONE 32x32 quadrant per phase
// (QK VALU per wave halves). PV: wave w = e-tile w, single q-tile A-frag,
// 4 MFMA per tile. Waves 4-7 keep K-staging (heterogeneity = R12 lesson).
// Cost: 2x V-L2 traffic (~3.7 TB/s per XCD, under ~4.6 ceiling).
// l-partials 8-way (kh x tp x ks2) -> lp8; proj sums 8.
// ---------------------------------------------------------------------------
#define K_STAGE2(TNEXT, KSW)                                                  \
  if (tid >= 256) {                                                           \
    *(uint4v*)&Ks[(KSW) * 2304 + skr * 36 + skc] = kregA;                     \
    *(uint4v*)&Ks[((KSW) + 1) * 2304 + skr * 36 + skc] = kregB;               \
    int ta_ = (TNEXT) > 31 ? 31 : (TNEXT);                                    \
    int tb_ = (TNEXT) + 1 > 31 ? 31 : (TNEXT) + 1;                            \
    kregA =                                                                   \
        *(const uint4v*)&qkb[(size_t)(mbase + ta_ * 64 + skr) * 64 + 32 + skc]; \
    kregB =                                                                   \
        *(const uint4v*)&qkb[(size_t)(mbase + tb_ * 64 + skr) * 64 + 32 + skc]; \
  }

// QK pair: wave w<4 computes ONE quadrant (tile BASE+tp, key-half ks2) of
// S^T for the block's 32 q-rows; exp2 + pack into Pbuf[BASE+tp].
#define QK_PAIR(BASE)                                                         \
  if (w < 4) {                                                                \
    int qb_ = (BASE) + tp;                                                    \
    float16v st;                                                              \
    _Pragma("unroll") for (int r = 0; r < 16; r++) st[r] = 0.f;               \
    __builtin_amdgcn_s_setprio(1);                                            \
    _Pragma("unroll") for (int s = 0; s < 2; s++) {                           \
      bf16x8 af = *(const bf16x8*)&Ks[qb_ * 2304 + (32 * ks2 + l31) * 36 +    \
                                      16 * s + 8 * hh];                       \
      st = __builtin_amdgcn_mfma_f32_32x32x16_bf16(af, qfr[s], st, 0, 0, 0);  \
    }                                                                         \
    __builtin_amdgcn_s_setprio(0);                                            \
    _Pragma("unroll") for (int rq = 0; rq < 4; rq++) {                        \
      float e0 = EXP2(st[4 * rq + 0]);                                        \
      float e1 = EXP2(st[4 * rq + 1]);                                        \
      float e2 = EXP2(st[4 * rq + 2]);                                        \
      float e3 = EXP2(st[4 * rq + 3]);                                        \
      lsum += (e0 + e1) + (e2 + e3);                                          \
      uint2v pw;                                                              \
      pw[0] = __builtin_amdgcn_perm(__float_as_uint(e1), __float_as_uint(e0), \
                                    0x07060302u);                             \
      pw[1] = __builtin_amdgcn_perm(__float_as_uint(e3), __float_as_uint(e2), \
                                    0x07060302u);                             \
      *(uint2v*)&Pbuf[qb_ * 2176 + l31 * 68 + 8 * rq + 4 * hh + 32 * ks2] =   \
          pw;                                                                 \
    }                                                                         \
  }

#define PV_ONE(PBB, VS)                                                       \
  {                                                                           \
    __builtin_amdgcn_s_setprio(1);                                            \
    _Pragma("unroll") for (int sp = 0; sp < 4; sp++) {                        \
      bf16x8 a0 = *(const bf16x8*)&Pbuf[(PBB) * 2176 + l31 * 68 + 16 * sp +   \
                                        8 * hh];                              \
      acc =                                                                   \
          __builtin_amdgcn_mfma_f32_32x32x16_bf16(a0, VS[sp], acc, 0, 0, 0);  \
    }                                                                         \
    __builtin_amdgcn_s_setprio(0);                                            \
  }

#define V_LOAD2(T)                                                            \
  {                                                                           \
    const unsigned short* vp0_ = vbase + (size_t)(T)*16384;                   \
    const unsigned short* vp1_ = vbase + (size_t)((T) + 1) * 16384;           \
    _Pragma("unroll") for (int u = 0; u < 4; u++) {                           \
      vS0[u] = *(const bf16x8*)(vp0_ + u * 512);                              \
      vS1[u] = *(const bf16x8*)(vp1_ + u * 512);                              \
    }                                                                         \
  }

__global__ __launch_bounds__(512, 8) void attn_fused(
    const unsigned short* __restrict__ qk, const unsigned short* __restrict__ Vp,
    unsigned short* __restrict__ Pa, unsigned short* __restrict__ Pb,
    float* __restrict__ lp8) {
  int L = blockIdx.x;
  int xv = L & 7;          // XCD id (mod-8 round-robin)
  int b = xv >> 1;         // batch pinned to XCD pair-group
  int kh = xv & 1;         // key half pinned to XCD
  int n0 = (L >> 3) * 32;  // q-tile base (32 rows)
  int tid = threadIdx.x, lane = tid & 63, w = tid >> 6;
  int l31 = lane & 31, hh = lane >> 5;
  int tp = (w >> 1) & 1, ks2 = w & 1;  // QK roles (waves 0..3)

  __shared__ unsigned short Ks[4 * 2304];    // 4 x 64 keys x 36 (pad)
  __shared__ unsigned short Pbuf[4 * 2176];  // 4 x [32 q][68 keys(pad)]

  const unsigned short* qkb = qk + (size_t)b * NT * 64;
  const unsigned short* vit = Vp + ((size_t)b * 64 + kh * 32) * 16384;
  const unsigned short* vbase = vit + (size_t)w * 4 * 512 + lane * 8;

  bf16x8 qfr[2];
  if (w < 4) {
    int n_g = n0 + l31;
    qfr[0] = *(const bf16x8*)&qkb[(size_t)n_g * 64 + 8 * hh];
    qfr[1] = *(const bf16x8*)&qkb[(size_t)n_g * 64 + 8 * hh + 16];
  }

  int tK = tid - 256;
  int skr = tK >> 2, skc = (tK & 3) * 8;
  int mbase = kh * 2048;
  uint4v kregA, kregB;

  float16v acc;  // q-rows n0..n0+32, e-tile = w
#pragma unroll
  for (int r = 0; r < 16; r++) acc[r] = 0.f;
  float lsum = 0.f;

  bf16x8 vS0[4], vS1[4];
  // prologue: stage Ks[0],Ks[1] (tiles 0,1); kregs <- tiles 2,3
  if (tid >= 256) {
    kregA = *(const uint4v*)&qkb[(size_t)(mbase + skr) * 64 + 32 + skc];
    kregB = *(const uint4v*)&qkb[(size_t)(mbase + 64 + skr) * 64 + 32 + skc];
    *(uint4v*)&Ks[skr * 36 + skc] = kregA;
    *(uint4v*)&Ks[2304 + skr * 36 + skc] = kregB;
    kregA = *(const uint4v*)&qkb[(size_t)(mbase + 128 + skr) * 64 + 32 + skc];
    kregB = *(const uint4v*)&qkb[(size_t)(mbase + 192 + skr) * 64 + 32 + skc];
  }
  BARRIER();

  // phase 0 (tiles 0,1; no PV)
  K_STAGE2(4, 2);
  QK_PAIR(0);
  V_LOAD2(0);
  BARRIER();

  for (int p = 1; p < 15; p += 2) {
    // odd phase p: tiles 2p,2p+1 via bufs {2,3}; PV tiles 2p-2,2p-1 bufs {0,1}
    K_STAGE2(2 * p + 4, 0);
    QK_PAIR(2);
    PV_ONE(0, vS0);
    PV_ONE(1, vS1);
    V_LOAD2(2 * p);
    BARRIER();
    // even phase p+1: tiles 2p+2,2p+3 via bufs {0,1}; PV bufs {2,3}
    K_STAGE2(2 * p + 6, 2);
    QK_PAIR(0);
    PV_ONE(2, vS0);
    PV_ONE(3, vS1);
    V_LOAD2(2 * p + 2);
    BARRIER();
  }
  // phase 15: tiles 30,31 via bufs {2,3}; PV tiles 28,29 bufs {0,1}
  K_STAGE2(34, 0);  // clamped loads; Ks[0],[1] writes unused afterwards
  QK_PAIR(2);
  PV_ONE(0, vS0);
  PV_ONE(1, vS1);
  V_LOAD2(30);
  BARRIER();
  // epilogue: PV tiles 30,31
  PV_ONE(2, vS0);
  PV_ONE(3, vS1);

  // l partials: wave (tp,ks2) covers keys {64t+32ks2..+32 : t parity tp};
  // combine hh halves; slot = kh*4 + w (8-way per batch).
  if (w < 4) {
    lsum += __shfl_xor(lsum, 32);
    if (hh == 0) {
      lp8[(size_t)((kh * 4 + w) * NB + b) * NT + n0 + l31] = lsum;
    }
  }

  // unnormalized partial O: wave w owns e-cols [32w, 32w+32), 32 q-rows
  unsigned short* Pout = (kh ? Pb : Pa) + (size_t)b * NT * CD;
#pragma unroll
  for (int r = 0; r < 16; r++) {
    int nl = (r & 3) + 8 * (r >> 2) + 4 * hh;
    Pout[(size_t)(n0 + nl) * CD + 32 * w + l31] = f2bf(acc[r]);
  }
}

// ---------------------------------------------------------------------------
// Proj GEMM (R13 structure; l-partials now 8-way).
// ---------------------------------------------------------------------------
__global__ __launch_bounds__(256) void proj_gemm(
    const unsigned short* __restrict__ Wp, const unsigned short* __restrict__ Pa,
    const unsigned short* __restrict__ Pb, const float* __restrict__ lp8,
    const float* __restrict__ bp, const float* __restrict__ x,
    float* __restrict__ out) {
  int nt = blockIdx.x, mh = blockIdx.y, b = blockIdx.z;
  int tid = threadIdx.x, lane = tid & 63;
  int w = tid >> 6;
  int l31 = lane & 31, hh = lane >> 5;
  int n0 = nt * 32;

  __shared__ unsigned short Bs[32 * 262];
  {
    int row = tid >> 3, c8 = (tid & 7) * 8;
    float lA = 0.f;
#pragma unroll
    for (int s4 = 0; s4 < 8; s4++)
      lA += lp8[(size_t)(s4 * NB + b) * NT + n0 + row];
    float inv = 1.f / lA;
#pragma unroll
    for (int u = 0; u < 4; u++) {
      int col = c8 + u * 64;
      size_t goff = ((size_t)b * NT + n0 + row) * CD + col;
      uint4v ua = *(const uint4v*)(Pa + goff);
      uint4v ub = *(const uint4v*)(Pb + goff);
      uint4v rr;
#pragma unroll
      for (int j = 0; j < 4; j++) {
        float lo = __uint_as_float(ua[j] << 16) + __uint_as_float(ub[j] << 16);
        float hi = __uint_as_float(ua[j] & 0xffff0000u) +
                   __uint_as_float(ub[j] & 0xffff0000u);
        lo *= inv;
        hi *= inv;
        rr[j] = __builtin_amdgcn_perm(__float_as_uint(hi), __float_as_uint(lo),
                                      0x07060302u);
      }
      *(uint4v*)&Bs[row * 262 + col] = rr;
    }
  }
  __syncthreads();

  int m_base = mh * 128 + w * 32;
  const unsigned short* Arow = Wp + (size_t)(m_base + l31) * 256 + 8 * hh;
  const unsigned short* b0p = &Bs[l31 * 262 + 8 * hh];
  float16v acc;
#pragma unroll
  for (int r = 0; r < 16; r++) acc[r] = 0.f;
#pragma unroll
  for (int s = 0; s < 16; s++) {
    bf16x8 af = *(const bf16x8*)(Arow + 16 * s);
    bf16x8 bf0 = *(const bf16x8*)(b0p + 16 * s);
    acc = __builtin_amdgcn_mfma_f32_32x32x16_bf16(af, bf0, acc, 0, 0, 0);
  }
  int n = n0 + l31;
#pragma unroll
  for (int r = 0; r < 16; r++) {
    int f = m_base + (r & 3) + 8 * (r >> 2) + 4 * hh;
    size_t idx = ((size_t)b * CD + f) * NT + n;
    out[idx] = x[idx] + acc[r] + bp[f];
  }
}

extern "C" void kernel_launch(void* const* d_in, const int* in_sizes, int n_in,
                              void* d_out, int out_size, void* d_ws,
                              size_t ws_size, hipStream_t stream) {
  (void)in_sizes; (void)n_in; (void)out_size; (void)ws_size;
  const float* x = (const float*)d_in[0];
  const float* gamma = (const float*)d_in[1];
  const float* beta = (const float*)d_in[2];
  const float* wq = (const float*)d_in[3];
  const float* bq = (const float*)d_in[4];
  const float* wk = (const float*)d_in[5];
  const float* bk = (const float*)d_in[6];
  const float* wv = (const float*)d_in[7];
  const float* bv = (const float*)d_in[8];
  const float* wp = (const float*)d_in[9];
  const float* bp = (const float*)d_in[10];
  float* out = (float*)d_out;

  char* ws = (char*)d_ws;
  unsigned short* pa_ws = (unsigned short*)ws;              // 8 MB (Pa)
  unsigned short* qk_ws = (unsigned short*)(ws + 8388608);  // 2 MB
  unsigned short* v_ws = (unsigned short*)(ws + 10485760);  // 8 MB (packed V)
  unsigned short* o_ws = (unsigned short*)(ws + 18874368);  // 8 MB (Pb)
  unsigned short* wqkv_b = (unsigned short*)(ws + 27262976);  // 160 KB
  unsigned short* wp_b = (unsigned short*)(ws + 27426816);    // 128 KB
  float* bias_q = (float*)(ws + 27557888);                    // 1.25 KB
  float* lp8 = (float*)(ws + 27563264);                       // 512 KB
  float* sc_ws = (float*)(ws + 28087552);                     // 4 KB
  float* sh_ws = (float*)(ws + 28091648);                     // 4 KB

  stats_pack<<<273, 1024, 0, stream>>>(x, gamma, beta, wq, wk, wv, wp, bq, bk,
                                       bv, sc_ws, sh_ws, wqkv_b, wp_b, bias_q);
  dim3 gq(128, NB);
  qkv_norm<<<gq, 512, 0, stream>>>(x, sc_ws, sh_ws, wqkv_b, bias_q, qk_ws,
                                   v_ws);
  attn_fused<<<1024, 512, 0, stream>>>(qk_ws, v_ws, pa_ws, o_ws, lp8);
  dim3 gp(128, 2, NB);
  proj_gemm<<<gp, 256, 0, stream>>>(wp_b, pa_ws, o_ws, lp8, bp, x, out);
}

// Round 12
// 168.866 us; speedup vs baseline: 2.3259x; 2.3259x over previous
//
#include <hip/hip_runtime.h>
#include <hip/hip_bf16.h>

// Problem constants (B=4, C=256, H=W=64, N=4096, G=32, DQK=32)
#define NB 4
#define CD 256
#define NT 4096
#define DQ 32

typedef __attribute__((ext_vector_type(8))) __bf16 bf16x8;
typedef __attribute__((ext_vector_type(16))) float float16v;
typedef __attribute__((ext_vector_type(4))) unsigned int uint4v;
typedef __attribute__((ext_vector_type(2))) unsigned int uint2v;

#if __has_builtin(__builtin_amdgcn_exp2f)
#define EXP2(x) __builtin_amdgcn_exp2f(x)
#else
#define EXP2(x) exp2f(x)
#endif

__device__ inline unsigned short f2bf(float f) {
  unsigned u = __float_as_uint(f);
  u += 0x7fffu + ((u >> 16) & 1u);
  return (unsigned short)(u >> 16);
}

// Raw barrier: LDS ordering only. Global loads into registers stay IN FLIGHT
// across it (compiler __syncthreads() forces vmcnt(0) drain = R7's 99us).
#define BARRIER() asm volatile("s_waitcnt lgkmcnt(0)\n\ts_barrier" ::: "memory")

// ---------------------------------------------------------------------------
// Stats + weight packing.
// ---------------------------------------------------------------------------
__global__ __launch_bounds__(1024) void stats_pack(
    const float* __restrict__ x, const float* __restrict__ gamma,
    const float* __restrict__ beta, const float* __restrict__ wq,
    const float* __restrict__ wk, const float* __restrict__ wv,
    const float* __restrict__ wp, const float* __restrict__ bq,
    const float* __restrict__ bk, const float* __restrict__ bv,
    float* __restrict__ sc, float* __restrict__ sh,
    unsigned short* __restrict__ wqkv, unsigned short* __restrict__ wpb,
    float* __restrict__ bias) {
  int bx = blockIdx.x;
  int tid = threadIdx.x;
  if (bx < 128) {
    int b = bx >> 5, g = bx & 31;
    const float4* xp = (const float4*)(x + (size_t)bx * 32768);
    float s = 0.f, ss = 0.f;
#pragma unroll
    for (int i = 0; i < 8; i++) {
      float4 t4 = xp[i * 1024 + tid];
      s += t4.x + t4.y + t4.z + t4.w;
      ss += t4.x * t4.x + t4.y * t4.y + t4.z * t4.z + t4.w * t4.w;
    }
#pragma unroll
    for (int off = 32; off >= 1; off >>= 1) {
      s += __shfl_xor(s, off);
      ss += __shfl_xor(ss, off);
    }
    __shared__ float red[32];
    int wid = tid >> 6;
    if ((tid & 63) == 0) {
      red[wid] = s;
      red[16 + wid] = ss;
    }
    __syncthreads();
    if (tid < 8) {
      float S = 0.f, SS = 0.f;
#pragma unroll
      for (int i = 0; i < 16; i++) {
        S += red[i];
        SS += red[16 + i];
      }
      float mu = S * (1.f / 32768.f);
      float rstd = rsqrtf(SS * (1.f / 32768.f) - mu * mu + 1e-5f);
      int c = g * 8 + tid;
      float gm = gamma[c];
      sc[b * CD + c] = gm * rstd;
      sh[b * CD + c] = beta[c] - mu * gm * rstd;
    }
  } else {
    const float scale2 = 0.2550348909867343f;  // log2(e)/sqrt(32)
    int i = (bx - 128) * 1024 + tid;
    if (i < 320 * 256) {
      int j = i >> 8, c = i & 255;
      float v;
      if (j < 32) v = wq[j * 256 + c] * scale2;
      else if (j < 64) v = wk[(j - 32) * 256 + c];
      else v = wv[(j - 64) * 256 + c];
      wqkv[i] = f2bf(v);
    } else if (i < 320 * 256 + 256 * 256) {
      int k = i - 320 * 256;
      wpb[k] = f2bf(wp[k]);
    } else if (i < 320 * 256 + 256 * 256 + 320) {
      int j = i - (320 * 256 + 256 * 256);
      float v;
      if (j < 32) v = bq[j] * scale2;
      else if (j < 64) v = bk[j - 32];
      else v = bv[j - 64];
      bias[j] = v;
    }
  }
}

// ---------------------------------------------------------------------------
// Fused normalize + QKV GEMM (R13: 32-n tiles, 512 blocks, all 8 waves MFMA).
// ---------------------------------------------------------------------------
__global__ __launch_bounds__(512) void qkv_norm(
    const float* __restrict__ x, const float* __restrict__ sc,
    const float* __restrict__ sh, const unsigned short* __restrict__ A,
    const float* __restrict__ bias, unsigned short* __restrict__ qk,
    unsigned short* __restrict__ v) {
  int nt = blockIdx.x, b = blockIdx.y;
  int tid = threadIdx.x, lane = tid & 63, w = tid >> 6;
  int l31 = lane & 31, hh = lane >> 5;
  int n0 = nt * 32;

  __shared__ unsigned short Hs[32 * 262];
  const float* xb = x + (size_t)b * CD * NT + n0;
  const float* scb = sc + b * CD;
  const float* shb = sh + b * CD;
  {
    int n_l = tid & 31, cg = tid >> 5;  // 16 c-groups of 16 channels
    int c0 = cg * 16;
    unsigned short hv[16];
#pragma unroll
    for (int j = 0; j < 16; j++) {
      float val = xb[(size_t)(c0 + j) * NT + n_l];
      hv[j] = f2bf(val * scb[c0 + j] + shb[c0 + j]);
    }
    *(uint4v*)&Hs[n_l * 262 + c0] = *(uint4v*)hv;
    *(uint4v*)&Hs[n_l * 262 + c0 + 8] = *(uint4v*)(hv + 8);
  }
  __syncthreads();

  int n = n0 + l31;
  int itg = n >> 6, sp = (n >> 4) & 3;
  int lsn = ((n >> 3) & 1) * 32;
  int el = n & 7;
  const unsigned short* Brow = &Hs[l31 * 262 + 8 * hh];
  for (int t = w; t < 10; t += 8) {
    int m_base = t * 32;
    const unsigned short* Arow = A + (size_t)(m_base + l31) * 256 + 8 * hh;
    float16v acc;
#pragma unroll
    for (int r = 0; r < 16; r++) acc[r] = 0.f;
#pragma unroll
    for (int s = 0; s < 16; s++) {
      bf16x8 af = *(const bf16x8*)(Arow + 16 * s);
      bf16x8 bf = *(const bf16x8*)(Brow + 16 * s);
      acc = __builtin_amdgcn_mfma_f32_32x32x16_bf16(af, bf, acc, 0, 0, 0);
    }
#pragma unroll
    for (int r = 0; r < 16; r++) {
      int j = m_base + (r & 3) + 8 * (r >> 2) + 4 * hh;
      float val = acc[r] + bias[j];
      if (j < 64) {
        qk[((size_t)b * NT + n) * 64 + j] = f2bf(val);
      } else {
        int e = j - 64;
        int et = e >> 5;
        v[((((size_t)b * 64 + itg) * 8 + et) * 4 + sp) * 512 +
          (lsn + (e & 31)) * 8 + el] = f2bf(val);
      }
    }
  }
}

// ---------------------------------------------------------------------------
// Fused attention: VERBATIM R11/R13 (measured 45.3-45.6us across 10+ runs,
// session-verified stable). Two independent 8-wave/SIMD attempts (R14:
// 1024-thread, R16: 32-row q-tiles) BOTH spilled: the schedule's true VGPR
// high-water mark (vS dbuf 32 + acc + QK's st16 temp + addressing) exceeds
// the 64-reg/8-wave budget; allocator spills -> ~1GB scratch traffic ->
// 280-360us. 4 waves/SIMD is this schedule's occupancy ceiling; its 45us
// operating point stands. Heterogeneous wave roles kept (R12: balancing
// regressed); one counted-vmcnt barrier per 2 K-tiles (R11).
// ---------------------------------------------------------------------------
#define K_STAGE2(TNEXT, KSW)                                                  \
  if (tid >= 256) {                                                           \
    *(uint4v*)&Ks[(KSW) * 2304 + skr * 36 + skc] = kregA;                     \
    *(uint4v*)&Ks[((KSW) + 1) * 2304 + skr * 36 + skc] = kregB;               \
    int ta_ = (TNEXT) > 31 ? 31 : (TNEXT);                                    \
    int tb_ = (TNEXT) + 1 > 31 ? 31 : (TNEXT) + 1;                            \
    kregA =                                                                   \
        *(const uint4v*)&qkb[(size_t)(mbase + ta_ * 64 + skr) * 64 + 32 + skc]; \
    kregB =                                                                   \
        *(const uint4v*)&qkb[(size_t)(mbase + tb_ * 64 + skr) * 64 + 32 + skc]; \
  }

#define QK_ONE(KSB, PBB)                                                      \
  if (w < 4) {                                                                \
    float16v st;                                                              \
    _Pragma("unroll") for (int r = 0; r < 16; r++) st[r] = 0.f;               \
    __builtin_amdgcn_s_setprio(1);                                            \
    _Pragma("unroll") for (int s = 0; s < 2; s++) {                           \
      bf16x8 af = *(const bf16x8*)&Ks[(KSB) * 2304 + (32 * ks2 + l31) * 36 +  \
                                      16 * s + 8 * hh];                       \
      st = __builtin_amdgcn_mfma_f32_32x32x16_bf16(af, qfr[s], st, 0, 0, 0);  \
    }                                                                         \
    __builtin_amdgcn_s_setprio(0);                                            \
    _Pragma("unroll") for (int rq = 0; rq < 4; rq++) {                        \
      float e0 = EXP2(st[4 * rq + 0]);                                        \
      float e1 = EXP2(st[4 * rq + 1]);                                        \
      float e2 = EXP2(st[4 * rq + 2]);                                        \
      float e3 = EXP2(st[4 * rq + 3]);                                        \
      lsum += (e0 + e1) + (e2 + e3);                                          \
      uint2v pw;                                                              \
      pw[0] = __builtin_amdgcn_perm(__float_as_uint(e1), __float_as_uint(e0), \
                                    0x07060302u);                             \
      pw[1] = __builtin_amdgcn_perm(__float_as_uint(e3), __float_as_uint(e2), \
                                    0x07060302u);                             \
      *(uint2v*)&Pbuf[(PBB) * 4352 + (qs * 32 + l31) * 68 + 8 * rq + 4 * hh + \
                      32 * ks2] = pw;                                         \
    }                                                                         \
  }

#define PV_ONE(PBB, VS)                                                       \
  {                                                                           \
    __builtin_amdgcn_s_setprio(1);                                            \
    _Pragma("unroll") for (int sp = 0; sp < 4; sp++) {                        \
      bf16x8 a0 =                                                             \
          *(const bf16x8*)&Pbuf[(PBB) * 4352 + l31 * 68 + 16 * sp + 8 * hh];  \
      bf16x8 a1 = *(const bf16x8*)&Pbuf[(PBB) * 4352 + (32 + l31) * 68 +      \
                                        16 * sp + 8 * hh];                    \
      acc[0] =                                                                \
          __builtin_amdgcn_mfma_f32_32x32x16_bf16(a0, VS[sp], acc[0], 0, 0, 0); \
      acc[1] =                                                                \
          __builtin_amdgcn_mfma_f32_32x32x16_bf16(a1, VS[sp], acc[1], 0, 0, 0); \
    }                                                                         \
    __builtin_amdgcn_s_setprio(0);                                            \
  }

#define V_LOAD2(T)                                                            \
  {                                                                           \
    const unsigned short* vp0_ = vbase + (size_t)(T)*16384;                   \
    const unsigned short* vp1_ = vbase + (size_t)((T) + 1) * 16384;           \
    _Pragma("unroll") for (int u = 0; u < 4; u++) {                           \
      vS0[u] = *(const bf16x8*)(vp0_ + u * 512);                              \
      vS1[u] = *(const bf16x8*)(vp1_ + u * 512);                              \
    }                                                                         \
  }

__global__ __launch_bounds__(512, 4) void attn_fused(
    const unsigned short* __restrict__ qk, const unsigned short* __restrict__ Vp,
    unsigned short* __restrict__ Pa, unsigned short* __restrict__ Pb,
    float* __restrict__ lp4) {
  int L = blockIdx.x;
  int xv = L & 7;          // XCD id (mod-8 round-robin)
  int b = xv >> 1;         // batch pinned to XCD pair-group
  int kh = xv & 1;         // key half pinned to XCD
  int n0 = (L >> 3) * 64;  // q-tile base
  int tid = threadIdx.x, lane = tid & 63, w = tid >> 6;
  int l31 = lane & 31, hh = lane >> 5;
  int qs = w & 1, ks2 = (w >> 1) & 1;  // QK quadrant roles (waves 0..3)

  __shared__ unsigned short Ks[4 * 2304];    // 4 x 64 keys x 36 (pad)
  __shared__ unsigned short Pbuf[4 * 4352];  // 4 x [64 q][68 keys(pad)]

  const unsigned short* qkb = qk + (size_t)b * NT * 64;
  const unsigned short* vit = Vp + ((size_t)b * 64 + kh * 32) * 16384;
  const unsigned short* vbase = vit + (size_t)w * 4 * 512 + lane * 8;

  bf16x8 qfr[2];
  if (w < 4) {
    int n_g = n0 + 32 * qs + l31;
    qfr[0] = *(const bf16x8*)&qkb[(size_t)n_g * 64 + 8 * hh];
    qfr[1] = *(const bf16x8*)&qkb[(size_t)n_g * 64 + 8 * hh + 16];
  }

  int tK = tid - 256;
  int skr = tK >> 2, skc = (tK & 3) * 8;
  int mbase = kh * 2048;
  uint4v kregA, kregB;

  float16v acc[2];  // [q-half], e-tile = w
#pragma unroll
  for (int q2 = 0; q2 < 2; q2++)
#pragma unroll
    for (int r = 0; r < 16; r++) acc[q2][r] = 0.f;
  float lsum = 0.f;

  bf16x8 vS0[4], vS1[4];
  // prologue: stage Ks[0],Ks[1] (tiles 0,1); kregs <- tiles 2,3
  if (tid >= 256) {
    kregA = *(const uint4v*)&qkb[(size_t)(mbase + skr) * 64 + 32 + skc];
    kregB = *(const uint4v*)&qkb[(size_t)(mbase + 64 + skr) * 64 + 32 + skc];
    *(uint4v*)&Ks[skr * 36 + skc] = kregA;
    *(uint4v*)&Ks[2304 + skr * 36 + skc] = kregB;
    kregA = *(const uint4v*)&qkb[(size_t)(mbase + 128 + skr) * 64 + 32 + skc];
    kregB = *(const uint4v*)&qkb[(size_t)(mbase + 192 + skr) * 64 + 32 + skc];
  }
  BARRIER();

  // phase 0 (tiles 0,1; no PV)
  K_STAGE2(4, 2);
  QK_ONE(0, 0);
  QK_ONE(1, 1);
  V_LOAD2(0);
  BARRIER();

  for (int p = 1; p < 15; p += 2) {
    // odd phase p: tiles 2p,2p+1 via bufs {2,3}; PV tiles 2p-2,2p-1 bufs {0,1}
    K_STAGE2(2 * p + 4, 0);
    QK_ONE(2, 2);
    QK_ONE(3, 3);
    PV_ONE(0, vS0);
    PV_ONE(1, vS1);
    V_LOAD2(2 * p);
    BARRIER();
    // even phase p+1: tiles 2p+2,2p+3 via bufs {0,1}; PV bufs {2,3}
    K_STAGE2(2 * p + 6, 2);
    QK_ONE(0, 0);
    QK_ONE(1, 1);
    PV_ONE(2, vS0);
    PV_ONE(3, vS1);
    V_LOAD2(2 * p + 2);
    BARRIER();
  }
  // phase 15: tiles 30,31 via bufs {2,3}; PV tiles 28,29 bufs {0,1}
  K_STAGE2(34, 0);  // clamped loads; Ks[0],[1] writes unused afterwards
  QK_ONE(2, 2);
  QK_ONE(3, 3);
  PV_ONE(0, vS0);
  PV_ONE(1, vS1);
  V_LOAD2(30);
  BARRIER();
  // epilogue: PV tiles 30,31
  PV_ONE(2, vS0);
  PV_ONE(3, vS1);

  // l partials: wave (qs,ks2) holds keys 32ks2 range; combine hh halves
  if (w < 4) {
    lsum += __shfl_xor(lsum, 32);
    if (hh == 0) {
      lp4[(size_t)((kh * 2 + ks2) * NB + b) * NT + n0 + 32 * qs + l31] = lsum;
    }
  }

  // unnormalized partial O: wave w owns e-cols [32w, 32w+32)
  unsigned short* Pout = (kh ? Pb : Pa) + (size_t)b * NT * CD;
#pragma unroll
  for (int r = 0; r < 16; r++) {
    int nl = (r & 3) + 8 * (r >> 2) + 4 * hh;
    Pout[(size_t)(n0 + nl) * CD + 32 * w + l31] = f2bf(acc[0][r]);
    Pout[(size_t)(n0 + 32 + nl) * CD + 32 * w + l31] = f2bf(acc[1][r]);
  }
}

// ---------------------------------------------------------------------------
// Proj GEMM (R13: 32-n tiles, 1024 blocks, 4/CU).
// ---------------------------------------------------------------------------
__global__ __launch_bounds__(256) void proj_gemm(
    const unsigned short* __restrict__ Wp, const unsigned short* __restrict__ Pa,
    const unsigned short* __restrict__ Pb, const float* __restrict__ lp4,
    const float* __restrict__ bp, const float* __restrict__ x,
    float* __restrict__ out) {
  int nt = blockIdx.x, mh = blockIdx.y, b = blockIdx.z;
  int tid = threadIdx.x, lane = tid & 63;
  int w = tid >> 6;
  int l31 = lane & 31, hh = lane >> 5;
  int n0 = nt * 32;

  __shared__ unsigned short Bs[32 * 262];
  {
    int row = tid >> 3, c8 = (tid & 7) * 8;
    float lA = 0.f;
#pragma unroll
    for (int s4 = 0; s4 < 4; s4++)
      lA += lp4[(size_t)(s4 * NB + b) * NT + n0 + row];
    float inv = 1.f / lA;
#pragma unroll
    for (int u = 0; u < 4; u++) {
      int col = c8 + u * 64;
      size_t goff = ((size_t)b * NT + n0 + row) * CD + col;
      uint4v ua = *(const uint4v*)(Pa + goff);
      uint4v ub = *(const uint4v*)(Pb + goff);
      uint4v rr;
#pragma unroll
      for (int j = 0; j < 4; j++) {
        float lo = __uint_as_float(ua[j] << 16) + __uint_as_float(ub[j] << 16);
        float hi = __uint_as_float(ua[j] & 0xffff0000u) +
                   __uint_as_float(ub[j] & 0xffff0000u);
        lo *= inv;
        hi *= inv;
        rr[j] = __builtin_amdgcn_perm(__float_as_uint(hi), __float_as_uint(lo),
                                      0x07060302u);
      }
      *(uint4v*)&Bs[row * 262 + col] = rr;
    }
  }
  __syncthreads();

  int m_base = mh * 128 + w * 32;
  const unsigned short* Arow = Wp + (size_t)(m_base + l31) * 256 + 8 * hh;
  const unsigned short* b0p = &Bs[l31 * 262 + 8 * hh];
  float16v acc;
#pragma unroll
  for (int r = 0; r < 16; r++) acc[r] = 0.f;
#pragma unroll
  for (int s = 0; s < 16; s++) {
    bf16x8 af = *(const bf16x8*)(Arow + 16 * s);
    bf16x8 bf0 = *(const bf16x8*)(b0p + 16 * s);
    acc = __builtin_amdgcn_mfma_f32_32x32x16_bf16(af, bf0, acc, 0, 0, 0);
  }
  int n = n0 + l31;
#pragma unroll
  for (int r = 0; r < 16; r++) {
    int f = m_base + (r & 3) + 8 * (r >> 2) + 4 * hh;
    size_t idx = ((size_t)b * CD + f) * NT + n;
    out[idx] = x[idx] + acc[r] + bp[f];
  }
}

extern "C" void kernel_launch(void* const* d_in, const int* in_sizes, int n_in,
                              void* d_out, int out_size, void* d_ws,
                              size_t ws_size, hipStream_t stream) {
  (void)in_sizes; (void)n_in; (void)out_size; (void)ws_size;
  const float* x = (const float*)d_in[0];
  const float* gamma = (const float*)d_in[1];
  const float* beta = (const float*)d_in[2];
  const float* wq = (const float*)d_in[3];
  const float* bq = (const float*)d_in[4];
  const float* wk = (const float*)d_in[5];
  const float* bk = (const float*)d_in[6];
  const float* wv = (const float*)d_in[7];
  const float* bv = (const float*)d_in[8];
  const float* wp = (const float*)d_in[9];
  const float* bp = (const float*)d_in[10];
  float* out = (float*)d_out;

  char* ws = (char*)d_ws;
  unsigned short* pa_ws = (unsigned short*)ws;              // 8 MB (Pa)
  unsigned short* qk_ws = (unsigned short*)(ws + 8388608);  // 2 MB
  unsigned short* v_ws = (unsigned short*)(ws + 10485760);  // 8 MB (packed V)
  unsigned short* o_ws = (unsigned short*)(ws + 18874368);  // 8 MB (Pb)
  unsigned short* wqkv_b = (unsigned short*)(ws + 27262976);  // 160 KB
  unsigned short* wp_b = (unsigned short*)(ws + 27426816);    // 128 KB
  float* bias_q = (float*)(ws + 27557888);                    // 1.25 KB
  float* lp4 = (float*)(ws + 27563264);                       // 256 KB
  float* sc_ws = (float*)(ws + 27825408);                     // 4 KB
  float* sh_ws = (float*)(ws + 27829504);                     // 4 KB

  stats_pack<<<273, 1024, 0, stream>>>(x, gamma, beta, wq, wk, wv, wp, bq, bk,
                                       bv, sc_ws, sh_ws, wqkv_b, wp_b, bias_q);
  dim3 gq(128, NB);
  qkv_norm<<<gq, 512, 0, stream>>>(x, sc_ws, sh_ws, wqkv_b, bias_q, qk_ws,
                                   v_ws);
  attn_fused<<<512, 512, 0, stream>>>(qk_ws, v_ws, pa_ws, o_ws, lp4);
  dim3 gp(128, 2, NB);
  proj_gemm<<<gp, 256, 0, stream>>>(wp_b, pa_ws, o_ws, lp4, bp, x, out);
}